// Round 1
// baseline (1396.874 us; speedup 1.0000x reference)
//
#include <hip/hip_runtime.h>
#include <stdint.h>

#define E_ 8
#define D_ 1024
#define H_ 2048
#define O_ 1024
#define B_ 4096
#define GTOT (B_ * 2)        // total compact rows (every token to exactly 2 experts)
#define GPAD (GTOT + 128)    // pad: GEMM tiles may over-read up to 127 rows past count

typedef __attribute__((ext_vector_type(8))) __bf16 bf16x8;
typedef __attribute__((ext_vector_type(4))) float f32x4;
typedef unsigned short u16;
typedef __attribute__((ext_vector_type(4))) u16 u16x4;

__device__ __forceinline__ u16 f2bf(float f) {
    union { float f; uint32_t u; } v; v.f = f;
    uint32_t u = v.u;
    return (u16)((u + 0x7FFFu + ((u >> 16) & 1u)) >> 16);   // RNE
}

// async global->LDS, 16B per lane; LDS dest = base + lane*16 (wave-uniform base)
__device__ __forceinline__ void gl2lds16(const void* g, void* lds) {
    __builtin_amdgcn_global_load_lds(
        (__attribute__((address_space(1))) void*)(uintptr_t)g,
        (__attribute__((address_space(3))) void*)(uint32_t)(uintptr_t)lds,
        16, 0, 0);
}

struct XPtrs { const float* p[8]; };

// ---------------- gating: 1 wave per token, fp64 accumulation ----------------
__global__ void __launch_bounds__(256) gate_kernel(XPtrs xs, const float* __restrict__ gw,
                                                   const float* __restrict__ gb,
                                                   int* __restrict__ t2i, float* __restrict__ t2w) {
    int wave = threadIdx.x >> 6;
    int lane = threadIdx.x & 63;
    int b = blockIdx.x * 4 + wave;
    double acc[8];
#pragma unroll
    for (int e = 0; e < 8; ++e) acc[e] = 0.0;
    for (int ep = 0; ep < 8; ++ep) {
        const float* xr = xs.p[ep] + (size_t)b * D_;
        for (int t = 0; t < D_ / 64; ++t) {
            int d = t * 64 + lane;
            float v = xr[d];
            const float* g = gw + ((size_t)(ep * D_ + d)) * 8;
#pragma unroll
            for (int e = 0; e < 8; ++e) acc[e] += (double)v * (double)g[e];
        }
    }
#pragma unroll
    for (int e = 0; e < 8; ++e)
        for (int off = 32; off > 0; off >>= 1) acc[e] += __shfl_xor(acc[e], off, 64);
    if (lane == 0) {
        float lg[8];
#pragma unroll
        for (int e = 0; e < 8; ++e) lg[e] = (float)acc[e] + gb[e];
        int i0 = 0;
        for (int e = 1; e < 8; ++e) if (lg[e] > lg[i0]) i0 = e;   // strict > : lowest idx on tie (top_k semantics)
        int i1 = -1;
        for (int e = 0; e < 8; ++e) {
            if (e == i0) continue;
            if (i1 < 0 || lg[e] > lg[i1]) i1 = e;
        }
        float ex = expf(lg[i1] - lg[i0]);
        float w0 = 1.0f / (1.0f + ex);
        t2i[b * 2 + 0] = i0; t2i[b * 2 + 1] = i1;
        t2w[b * 2 + 0] = w0; t2w[b * 2 + 1] = ex * w0;
    }
}

// ---------------- routing: counts -> offsets (single block) ----------------
__global__ void __launch_bounds__(256) route_build(const int* __restrict__ t2i,
                                                   int* __restrict__ offs, int* __restrict__ cursor) {
    __shared__ int cnt[8];
    int t = threadIdx.x;
    if (t < 8) cnt[t] = 0;
    __syncthreads();
    for (int i = t; i < B_ * 2; i += 256) atomicAdd(&cnt[t2i[i]], 1);
    __syncthreads();
    if (t == 0) {
        int run = 0;
        for (int e = 0; e < 8; ++e) { offs[e] = run; cursor[e] = run; run += cnt[e]; }
        offs[8] = run;
    }
}

__global__ void __launch_bounds__(256) route_scatter(const int* __restrict__ t2i, int* __restrict__ cursor,
                                                     int* __restrict__ tok, int* __restrict__ etok,
                                                     int* __restrict__ slot) {
    int b = blockIdx.x * 256 + threadIdx.x;
#pragma unroll
    for (int j = 0; j < 2; ++j) {
        int e = t2i[b * 2 + j];
        int g = atomicAdd(&cursor[e], 1);
        tok[g] = b; etok[g] = e; slot[b * 2 + j] = g;
    }
}

// ---------------- gather tokens into compact bf16 A1 [GTOT][D] ----------------
__global__ void __launch_bounds__(256) gather_x(XPtrs xs, const int* __restrict__ tok,
                                                const int* __restrict__ etok, u16* __restrict__ A1) {
    int g = blockIdx.x;
    int t = threadIdx.x;
    const float4* s4 = (const float4*)(xs.p[etok[g]] + (size_t)tok[g] * D_);
    float4 v = s4[t];
    u16x4 o; o.x = f2bf(v.x); o.y = f2bf(v.y); o.z = f2bf(v.z); o.w = f2bf(v.w);
    ((u16x4*)(A1 + (size_t)g * D_))[t] = o;
}

// ---------------- weight transpose-convert: [E][K][N] f32 -> [E][N][K] bf16 ----------------
__global__ void __launch_bounds__(256) wconv(const float* __restrict__ w, u16* __restrict__ wt,
                                             int K, int N) {
    __shared__ float tile[32][33];
    int e = blockIdx.z;
    int n0 = blockIdx.x * 32, k0 = blockIdx.y * 32;
    int tx = threadIdx.x & 31, ty = threadIdx.x >> 5;   // ty 0..7
    const float* wp = w + (size_t)e * K * N;
#pragma unroll
    for (int r = 0; r < 4; ++r) {
        int k = ty + r * 8;
        tile[k][tx] = wp[(size_t)(k0 + k) * N + n0 + tx];
    }
    __syncthreads();
    u16* op = wt + (size_t)e * N * K;
#pragma unroll
    for (int r = 0; r < 4; ++r) {
        int n = ty + r * 8;
        op[(size_t)(n0 + n) * K + k0 + tx] = f2bf(tile[tx][n]);
    }
}

// ---------------- expert GEMM: C[cnt x N] = A[cnt x K] * Wt[e]^T (+bias, relu) ----------------
// 128x128 tile, BK=32, 4 waves (each 64x64 = 4x4 mfma_f32_16x16x32_bf16)
__global__ void __launch_bounds__(256) expert_gemm(const u16* __restrict__ A, const u16* __restrict__ Wt,
                                                   const float* __restrict__ bias,
                                                   u16* __restrict__ outB, float* __restrict__ outF,
                                                   const int* __restrict__ offs, int K, int N, int relu) {
    int e = blockIdx.z;
    int row0 = offs[e];
    int cnt = offs[e + 1] - row0;
    int mt = blockIdx.x;
    if (mt * 128 >= cnt) return;
    int nt = blockIdx.y;

    __shared__ __align__(16) u16 sA[128 * 32];
    __shared__ __align__(16) u16 sB[128 * 32];

    int tid = threadIdx.x;
    int wave = tid >> 6, lane = tid & 63;
    int wm = wave & 1, wn = wave >> 1;
    int l15 = lane & 15, quad = lane >> 4;

    f32x4 acc[4][4];
#pragma unroll
    for (int i = 0; i < 4; ++i)
#pragma unroll
        for (int j = 0; j < 4; ++j) acc[i][j] = (f32x4){0.f, 0.f, 0.f, 0.f};

    const int koff = (lane & 3) * 8;            // 8-elem (16B) chunk within BK=32
    const int rsub = lane >> 2;                 // 0..15 row within 16-row chunk
    const u16* Abase = A + (size_t)(row0 + mt * 128) * K;
    const u16* Bbase = Wt + ((size_t)e * N + (size_t)nt * 128) * K;

    int kSteps = K / 32;
    for (int ks = 0; ks < kSteps; ++ks) {
        int k0 = ks * 32;
        __syncthreads();                         // LDS safe to overwrite
#pragma unroll
        for (int c = 0; c < 2; ++c) {
            int ch = wave * 2 + c;               // 0..7, 16 rows each
            int r = ch * 16 + rsub;
            gl2lds16(Abase + (size_t)r * K + k0 + koff, &sA[ch * 512]);
            gl2lds16(Bbase + (size_t)r * K + k0 + koff, &sB[ch * 512]);
        }
        __syncthreads();                         // staging complete

        bf16x8 af[4], bfr[4];
#pragma unroll
        for (int tm = 0; tm < 4; ++tm) {
            int row = wm * 64 + tm * 16 + l15;
            af[tm] = *(const bf16x8*)&sA[row * 32 + quad * 8];
        }
#pragma unroll
        for (int tn = 0; tn < 4; ++tn) {
            int row = wn * 64 + tn * 16 + l15;
            bfr[tn] = *(const bf16x8*)&sB[row * 32 + quad * 8];
        }
#pragma unroll
        for (int tm = 0; tm < 4; ++tm)
#pragma unroll
            for (int tn = 0; tn < 4; ++tn)
                acc[tm][tn] = __builtin_amdgcn_mfma_f32_16x16x32_bf16(af[tm], bfr[tn], acc[tm][tn], 0, 0, 0);
    }

    // epilogue: C/D layout col=lane&15, row=quad*4+reg
    size_t gm0 = (size_t)row0 + (size_t)mt * 128 + (size_t)wm * 64;
    int lm0 = mt * 128 + wm * 64;
    int n0 = nt * 128 + wn * 64;
#pragma unroll
    for (int tn = 0; tn < 4; ++tn) {
        int col = n0 + tn * 16 + l15;
        float bv = bias[e * N + col];
#pragma unroll
        for (int tm = 0; tm < 4; ++tm) {
#pragma unroll
            for (int r = 0; r < 4; ++r) {
                int rr = tm * 16 + quad * 4 + r;
                if (lm0 + rr < cnt) {
                    float v = acc[tm][tn][r] + bv;
                    if (relu) v = fmaxf(v, 0.f);
                    if (outB) outB[(gm0 + rr) * N + col] = f2bf(v);
                    else      outF[(gm0 + rr) * N + col] = v;
                }
            }
        }
    }
}

// ---------------- combine: out[b] = w0*eo[slot0] + w1*eo[slot1] ----------------
__global__ void __launch_bounds__(256) combine_out(const float* __restrict__ eo, const int* __restrict__ slot,
                                                   const float* __restrict__ t2w, float* __restrict__ out) {
    int b = blockIdx.x, t = threadIdx.x;
    int g0 = slot[b * 2 + 0], g1 = slot[b * 2 + 1];
    float w0 = t2w[b * 2 + 0], w1 = t2w[b * 2 + 1];
    float4 va = ((const float4*)(eo + (size_t)g0 * O_))[t];
    float4 vc = ((const float4*)(eo + (size_t)g1 * O_))[t];
    float4 r;
    r.x = w0 * va.x + w1 * vc.x;
    r.y = w0 * va.y + w1 * vc.y;
    r.z = w0 * va.z + w1 * vc.z;
    r.w = w0 * va.w + w1 * vc.w;
    ((float4*)(out + (size_t)b * O_))[t] = r;
}

extern "C" void kernel_launch(void* const* d_in, const int* in_sizes, int n_in,
                              void* d_out, int out_size, void* d_ws, size_t ws_size,
                              hipStream_t stream) {
    (void)in_sizes; (void)n_in; (void)out_size; (void)ws_size;
    XPtrs xp;
    for (int i = 0; i < 8; ++i) xp.p[i] = (const float*)d_in[i];
    const float* gate_w = (const float*)d_in[8];
    const float* gate_b = (const float*)d_in[9];
    const float* w_in  = (const float*)d_in[10];
    const float* b_in  = (const float*)d_in[11];
    const float* w_h   = (const float*)d_in[12];
    const float* b_h   = (const float*)d_in[13];
    const float* w_out = (const float*)d_in[14];
    const float* b_out = (const float*)d_in[15];
    float* out = (float*)d_out;

    char* ws = (char*)d_ws;
    size_t off = 0;
    auto alloc = [&](size_t b) { size_t o = off; off += (b + 255) & ~(size_t)255; return o; };

    size_t t2i_o  = alloc((size_t)B_ * 2 * 4);
    size_t t2w_o  = alloc((size_t)B_ * 2 * 4);
    size_t slot_o = alloc((size_t)B_ * 2 * 4);
    size_t tok_o  = alloc((size_t)GTOT * 4);
    size_t etok_o = alloc((size_t)GTOT * 4);
    size_t offs_o = alloc(16 * 4);
    size_t cur_o  = alloc(8 * 4);
    size_t A1_o   = alloc((size_t)GPAD * D_ * 2);      // bf16 gathered inputs
    size_t h1_o   = alloc((size_t)GPAD * H_ * 2);      // bf16
    size_t h2_o   = alloc((size_t)GPAD * H_ * 2);      // bf16
    size_t wtin_o = alloc((size_t)E_ * H_ * D_ * 2);   // bf16 [e][n][k]
    size_t wth_o  = alloc((size_t)E_ * H_ * H_ * 2);
    size_t wtout_o= alloc((size_t)E_ * O_ * H_ * 2);
    size_t eo_o   = A1_o;   // alias: A1(+h1 head) dead by the time layer-3 writes eo

    int*   t2i  = (int*)(ws + t2i_o);
    float* t2w  = (float*)(ws + t2w_o);
    int*   slot = (int*)(ws + slot_o);
    int*   tok  = (int*)(ws + tok_o);
    int*   etok = (int*)(ws + etok_o);
    int*   offs = (int*)(ws + offs_o);
    int*   cur  = (int*)(ws + cur_o);
    u16*   A1   = (u16*)(ws + A1_o);
    u16*   h1   = (u16*)(ws + h1_o);
    u16*   h2   = (u16*)(ws + h2_o);
    u16*   wtin = (u16*)(ws + wtin_o);
    u16*   wth  = (u16*)(ws + wth_o);
    u16*   wtout= (u16*)(ws + wtout_o);
    float* eo   = (float*)(ws + eo_o);

    // gating + routing
    hipLaunchKernelGGL(gate_kernel, dim3(B_ / 4), dim3(256), 0, stream, xp, gate_w, gate_b, t2i, t2w);
    hipLaunchKernelGGL(route_build, dim3(1), dim3(256), 0, stream, t2i, offs, cur);
    hipLaunchKernelGGL(route_scatter, dim3(B_ / 256), dim3(256), 0, stream, t2i, cur, tok, etok, slot);
    hipLaunchKernelGGL(gather_x, dim3(GTOT), dim3(256), 0, stream, xp, tok, etok, A1);

    // weight convert+transpose (fp32 [E][K][N] -> bf16 [E][N][K])
    hipLaunchKernelGGL(wconv, dim3(H_ / 32, D_ / 32, E_), dim3(256), 0, stream, w_in, wtin, D_, H_);
    hipLaunchKernelGGL(wconv, dim3(H_ / 32, H_ / 32, E_), dim3(256), 0, stream, w_h, wth, H_, H_);
    hipLaunchKernelGGL(wconv, dim3(O_ / 32, H_ / 32, E_), dim3(256), 0, stream, w_out, wtout, H_, O_);

    // expert MLP: 3 GEMMs
    hipLaunchKernelGGL(expert_gemm, dim3(32, H_ / 128, E_), dim3(256), 0, stream,
                       A1, wtin, b_in, h1, (float*)nullptr, offs, D_, H_, 1);
    hipLaunchKernelGGL(expert_gemm, dim3(32, H_ / 128, E_), dim3(256), 0, stream,
                       h1, wth, b_h, h2, (float*)nullptr, offs, H_, H_, 1);
    hipLaunchKernelGGL(expert_gemm, dim3(32, O_ / 128, E_), dim3(256), 0, stream,
                       h2, wtout, b_out, (u16*)nullptr, eo, offs, H_, O_, 0);

    // weighted combine -> out (fully written, no zero-init needed)
    hipLaunchKernelGGL(combine_out, dim3(B_), dim3(256), 0, stream, eo, slot, t2w, out);
}

// Round 2
// 1220.366 us; speedup vs baseline: 1.1446x; 1.1446x over previous
//
#include <hip/hip_runtime.h>
#include <stdint.h>

#define E_ 8
#define D_ 1024
#define H_ 2048
#define O_ 1024
#define B_ 4096
#define GTOT (B_ * 2)        // total compact rows (every token to exactly 2 experts)
#define GPAD (GTOT + 128)    // pad: GEMM tiles may over-read up to 127 rows past count

typedef __attribute__((ext_vector_type(8))) __bf16 bf16x8;
typedef __attribute__((ext_vector_type(4))) float f32x4;
typedef unsigned short u16;
typedef __attribute__((ext_vector_type(4))) u16 u16x4;
typedef __attribute__((ext_vector_type(8))) u16 u16x8;

__device__ __forceinline__ u16 f2bf(float f) {
    union { float f; uint32_t u; } v; v.f = f;
    uint32_t u = v.u;
    return (u16)((u + 0x7FFFu + ((u >> 16) & 1u)) >> 16);   // RNE
}

// async global->LDS, 16B per lane; LDS dest = base + lane*16 (wave-uniform base)
__device__ __forceinline__ void gl2lds16(const void* g, void* lds) {
    __builtin_amdgcn_global_load_lds(
        (__attribute__((address_space(1))) void*)(uintptr_t)g,
        (__attribute__((address_space(3))) void*)(uint32_t)(uintptr_t)lds,
        16, 0, 0);
}

struct XPtrs { const float* p[8]; };

// ---------------- gating: 1 wave per token, fp64 accumulation ----------------
__global__ void __launch_bounds__(256) gate_kernel(XPtrs xs, const float* __restrict__ gw,
                                                   const float* __restrict__ gb,
                                                   int* __restrict__ t2i, float* __restrict__ t2w) {
    int wave = threadIdx.x >> 6;
    int lane = threadIdx.x & 63;
    int b = blockIdx.x * 4 + wave;
    double acc[8];
#pragma unroll
    for (int e = 0; e < 8; ++e) acc[e] = 0.0;
    for (int ep = 0; ep < 8; ++ep) {
        const float* xr = xs.p[ep] + (size_t)b * D_;
        for (int t = 0; t < D_ / 64; ++t) {
            int d = t * 64 + lane;
            float v = xr[d];
            const float* g = gw + ((size_t)(ep * D_ + d)) * 8;
#pragma unroll
            for (int e = 0; e < 8; ++e) acc[e] += (double)v * (double)g[e];
        }
    }
#pragma unroll
    for (int e = 0; e < 8; ++e)
        for (int off = 32; off > 0; off >>= 1) acc[e] += __shfl_xor(acc[e], off, 64);
    if (lane == 0) {
        float lg[8];
#pragma unroll
        for (int e = 0; e < 8; ++e) lg[e] = (float)acc[e] + gb[e];
        int i0 = 0;
        for (int e = 1; e < 8; ++e) if (lg[e] > lg[i0]) i0 = e;   // strict > : lowest idx on tie
        int i1 = -1;
        for (int e = 0; e < 8; ++e) {
            if (e == i0) continue;
            if (i1 < 0 || lg[e] > lg[i1]) i1 = e;
        }
        float ex = expf(lg[i1] - lg[i0]);
        float w0 = 1.0f / (1.0f + ex);
        t2i[b * 2 + 0] = i0; t2i[b * 2 + 1] = i1;
        t2w[b * 2 + 0] = w0; t2w[b * 2 + 1] = ex * w0;
    }
}

// ---------------- routing: counts -> offsets (single block) ----------------
__global__ void __launch_bounds__(256) route_build(const int* __restrict__ t2i,
                                                   int* __restrict__ offs, int* __restrict__ cursor) {
    __shared__ int cnt[8];
    int t = threadIdx.x;
    if (t < 8) cnt[t] = 0;
    __syncthreads();
    for (int i = t; i < B_ * 2; i += 256) atomicAdd(&cnt[t2i[i]], 1);
    __syncthreads();
    if (t == 0) {
        int run = 0;
        for (int e = 0; e < 8; ++e) { offs[e] = run; cursor[e] = run; run += cnt[e]; }
        offs[8] = run;
    }
}

__global__ void __launch_bounds__(256) route_scatter(const int* __restrict__ t2i, int* __restrict__ cursor,
                                                     int* __restrict__ tok, int* __restrict__ etok,
                                                     int* __restrict__ slot) {
    int b = blockIdx.x * 256 + threadIdx.x;
#pragma unroll
    for (int j = 0; j < 2; ++j) {
        int e = t2i[b * 2 + j];
        int g = atomicAdd(&cursor[e], 1);
        tok[g] = b; etok[g] = e; slot[b * 2 + j] = g;
    }
}

// ---------------- gather tokens into compact bf16 A1 [GTOT][D] ----------------
__global__ void __launch_bounds__(256) gather_x(XPtrs xs, const int* __restrict__ tok,
                                                const int* __restrict__ etok, u16* __restrict__ A1) {
    int g = blockIdx.x;
    int t = threadIdx.x;
    const float4* s4 = (const float4*)(xs.p[etok[g]] + (size_t)tok[g] * D_);
    float4 v = s4[t];
    u16x4 o; o.x = f2bf(v.x); o.y = f2bf(v.y); o.z = f2bf(v.z); o.w = f2bf(v.w);
    ((u16x4*)(A1 + (size_t)g * D_))[t] = o;
}

// ---------------- weight transpose-convert: [E][K][N] f32 -> [E][N][K] bf16 ----------------
// tile: 64 k x 32 n; writes 16B per thread (128B contiguous per n-row)
__global__ void __launch_bounds__(256) wconv(const float* __restrict__ w, u16* __restrict__ wt,
                                             int K, int N) {
    __shared__ float tile[64][33];
    int e = blockIdx.z;
    int n0 = blockIdx.x * 32, k0 = blockIdx.y * 64;
    int tid = threadIdx.x;
    int tx = tid & 31, ty = tid >> 5;
    const float* wp = w + (size_t)e * K * N + (size_t)k0 * N + n0;
#pragma unroll
    for (int r = 0; r < 8; ++r)
        tile[ty + r * 8][tx] = wp[(size_t)(ty + r * 8) * N + tx];
    __syncthreads();
    int n = tid >> 3, kq = tid & 7;
    u16x8 o;
#pragma unroll
    for (int i = 0; i < 8; ++i) o[i] = f2bf(tile[kq * 8 + i][n]);
    u16* op = wt + (size_t)e * N * K + (size_t)(n0 + n) * K + k0 + kq * 8;
    *(u16x8*)op = o;
}

// ---------------- expert GEMM: C[cnt x N] = A[cnt x K] * Wt[e]^T (+bias, relu) ----------------
// 128x128 tile, BK=32, 4 waves; 3-stage software pipeline:
//   loads for step k issued at step k-2, waited with s_waitcnt vmcnt(4) (never 0 except tail),
//   ONE raw s_barrier per step. XOR-swizzled k-chunks kill ds_read_b128 bank conflicts.
__global__ void __launch_bounds__(256) expert_gemm(const u16* __restrict__ A, const u16* __restrict__ Wt,
                                                   const float* __restrict__ bias,
                                                   u16* __restrict__ outB, float* __restrict__ outF,
                                                   const int* __restrict__ offs, int K, int N, int relu) {
    int e = blockIdx.z;
    int row0 = offs[e];
    int cnt = offs[e + 1] - row0;
    int mt = blockIdx.x;
    if (mt * 128 >= cnt) return;
    int nt = blockIdx.y;

    __shared__ __align__(16) u16 sA[3][128 * 32];
    __shared__ __align__(16) u16 sB[3][128 * 32];

    int tid = threadIdx.x;
    int wave = tid >> 6, lane = tid & 63;
    int wm = wave & 1, wn = wave >> 1;
    int l15 = lane & 15, quad = lane >> 4;
    int rsub = lane >> 2;                                    // 0..15 row within 16-row chunk
    // swizzle: logical k-chunk kc of row r lives at phys chunk kc ^ g(r), g(r)=(r&3)^((r>>2)&3)
    int koff = (((lane & 3) ^ (rsub & 3) ^ ((rsub >> 2) & 3)) * 8);   // global k offset for this lane's slot
    int physOff = (quad ^ (l15 & 3) ^ ((l15 >> 2) & 3)) * 8;          // LDS chunk offset for fragment reads

    f32x4 acc[4][4];
#pragma unroll
    for (int i = 0; i < 4; ++i)
#pragma unroll
        for (int j = 0; j < 4; ++j) acc[i][j] = (f32x4){0.f, 0.f, 0.f, 0.f};

    const u16* Abase = A + (size_t)(row0 + mt * 128) * K;
    const u16* Bbase = Wt + ((size_t)e * N + (size_t)nt * 128) * K;

    int kSteps = K / 32;

    auto issue = [&](int ks, int bufIdx) {
        int k0 = ks * 32;
        u16* dA = &sA[bufIdx][0];
        u16* dB = &sB[bufIdx][0];
#pragma unroll
        for (int c = 0; c < 2; ++c) {
            int ch = wave * 2 + c;                 // 0..7, 16 rows each
            int r = ch * 16 + rsub;
            gl2lds16(Abase + (size_t)r * K + k0 + koff, dA + ch * 512);
            gl2lds16(Bbase + (size_t)r * K + k0 + koff, dB + ch * 512);
        }
    };

    issue(0, 0);
    issue(1, 1);
    int bc = 0, bi = 2;
    for (int ks = 0; ks < kSteps; ++ks) {
        if (ks + 1 < kSteps) asm volatile("s_waitcnt vmcnt(4) lgkmcnt(0)" ::: "memory");
        else                 asm volatile("s_waitcnt vmcnt(0) lgkmcnt(0)" ::: "memory");
        __builtin_amdgcn_s_barrier();             // all waves' step-ks loads landed; step ks-1 reads done
        if (ks + 2 < kSteps) issue(ks + 2, bi);   // overwrites buffer last read at step ks-1 (safe)

        const u16* a_ = &sA[bc][0];
        const u16* b_ = &sB[bc][0];
        bf16x8 af[4], bfr[4];
#pragma unroll
        for (int tm = 0; tm < 4; ++tm) {
            int row = wm * 64 + tm * 16 + l15;
            af[tm] = *(const bf16x8*)(a_ + row * 32 + physOff);
        }
#pragma unroll
        for (int tn = 0; tn < 4; ++tn) {
            int row = wn * 64 + tn * 16 + l15;
            bfr[tn] = *(const bf16x8*)(b_ + row * 32 + physOff);
        }
#pragma unroll
        for (int tm = 0; tm < 4; ++tm)
#pragma unroll
            for (int tn = 0; tn < 4; ++tn)
                acc[tm][tn] = __builtin_amdgcn_mfma_f32_16x16x32_bf16(af[tm], bfr[tn], acc[tm][tn], 0, 0, 0);

        bc = (bc == 2) ? 0 : bc + 1;
        bi = (bi == 2) ? 0 : bi + 1;
    }

    // epilogue: C/D layout col=lane&15, row=quad*4+reg
    size_t gm0 = (size_t)row0 + (size_t)mt * 128 + (size_t)wm * 64;
    int lm0 = mt * 128 + wm * 64;
    int n0 = nt * 128 + wn * 64;
#pragma unroll
    for (int tn = 0; tn < 4; ++tn) {
        int col = n0 + tn * 16 + l15;
        float bv = bias[e * N + col];
#pragma unroll
        for (int tm = 0; tm < 4; ++tm) {
#pragma unroll
            for (int r = 0; r < 4; ++r) {
                int rr = tm * 16 + quad * 4 + r;
                if (lm0 + rr < cnt) {
                    float v = acc[tm][tn][r] + bv;
                    if (relu) v = fmaxf(v, 0.f);
                    if (outB) outB[(gm0 + rr) * N + col] = f2bf(v);
                    else      outF[(gm0 + rr) * N + col] = v;
                }
            }
        }
    }
}

// ---------------- combine: out[b] = w0*eo[slot0] + w1*eo[slot1] ----------------
__global__ void __launch_bounds__(256) combine_out(const float* __restrict__ eo, const int* __restrict__ slot,
                                                   const float* __restrict__ t2w, float* __restrict__ out) {
    int b = blockIdx.x, t = threadIdx.x;
    int g0 = slot[b * 2 + 0], g1 = slot[b * 2 + 1];
    float w0 = t2w[b * 2 + 0], w1 = t2w[b * 2 + 1];
    float4 va = ((const float4*)(eo + (size_t)g0 * O_))[t];
    float4 vc = ((const float4*)(eo + (size_t)g1 * O_))[t];
    float4 r;
    r.x = w0 * va.x + w1 * vc.x;
    r.y = w0 * va.y + w1 * vc.y;
    r.z = w0 * va.z + w1 * vc.z;
    r.w = w0 * va.w + w1 * vc.w;
    ((float4*)(out + (size_t)b * O_))[t] = r;
}

extern "C" void kernel_launch(void* const* d_in, const int* in_sizes, int n_in,
                              void* d_out, int out_size, void* d_ws, size_t ws_size,
                              hipStream_t stream) {
    (void)in_sizes; (void)n_in; (void)out_size; (void)ws_size;
    XPtrs xp;
    for (int i = 0; i < 8; ++i) xp.p[i] = (const float*)d_in[i];
    const float* gate_w = (const float*)d_in[8];
    const float* gate_b = (const float*)d_in[9];
    const float* w_in  = (const float*)d_in[10];
    const float* b_in  = (const float*)d_in[11];
    const float* w_h   = (const float*)d_in[12];
    const float* b_h   = (const float*)d_in[13];
    const float* w_out = (const float*)d_in[14];
    const float* b_out = (const float*)d_in[15];
    float* out = (float*)d_out;

    char* ws = (char*)d_ws;
    size_t off = 0;
    auto alloc = [&](size_t b) { size_t o = off; off += (b + 255) & ~(size_t)255; return o; };

    size_t t2i_o  = alloc((size_t)B_ * 2 * 4);
    size_t t2w_o  = alloc((size_t)B_ * 2 * 4);
    size_t slot_o = alloc((size_t)B_ * 2 * 4);
    size_t tok_o  = alloc((size_t)GTOT * 4);
    size_t etok_o = alloc((size_t)GTOT * 4);
    size_t offs_o = alloc(16 * 4);
    size_t cur_o  = alloc(8 * 4);
    size_t A1_o   = alloc((size_t)GPAD * D_ * 2);      // bf16 gathered inputs
    size_t h1_o   = alloc((size_t)GPAD * H_ * 2);      // bf16
    size_t h2_o   = alloc((size_t)GPAD * H_ * 2);      // bf16
    size_t wtin_o = alloc((size_t)E_ * H_ * D_ * 2);   // bf16 [e][n][k]
    size_t wth_o  = alloc((size_t)E_ * H_ * H_ * 2);
    size_t wtout_o= alloc((size_t)E_ * O_ * H_ * 2);
    size_t eo_o   = A1_o;   // alias: A1+h1 dead by the time layer-3 writes eo

    int*   t2i  = (int*)(ws + t2i_o);
    float* t2w  = (float*)(ws + t2w_o);
    int*   slot = (int*)(ws + slot_o);
    int*   tok  = (int*)(ws + tok_o);
    int*   etok = (int*)(ws + etok_o);
    int*   offs = (int*)(ws + offs_o);
    int*   cur  = (int*)(ws + cur_o);
    u16*   A1   = (u16*)(ws + A1_o);
    u16*   h1   = (u16*)(ws + h1_o);
    u16*   h2   = (u16*)(ws + h2_o);
    u16*   wtin = (u16*)(ws + wtin_o);
    u16*   wth  = (u16*)(ws + wth_o);
    u16*   wtout= (u16*)(ws + wtout_o);
    float* eo   = (float*)(ws + eo_o);

    // gating + routing
    hipLaunchKernelGGL(gate_kernel, dim3(B_ / 4), dim3(256), 0, stream, xp, gate_w, gate_b, t2i, t2w);
    hipLaunchKernelGGL(route_build, dim3(1), dim3(256), 0, stream, t2i, offs, cur);
    hipLaunchKernelGGL(route_scatter, dim3(B_ / 256), dim3(256), 0, stream, t2i, cur, tok, etok, slot);
    hipLaunchKernelGGL(gather_x, dim3(GTOT), dim3(256), 0, stream, xp, tok, etok, A1);

    // weight convert+transpose (fp32 [E][K][N] -> bf16 [E][N][K])
    hipLaunchKernelGGL(wconv, dim3(H_ / 32, D_ / 64, E_), dim3(256), 0, stream, w_in, wtin, D_, H_);
    hipLaunchKernelGGL(wconv, dim3(H_ / 32, H_ / 64, E_), dim3(256), 0, stream, w_h, wth, H_, H_);
    hipLaunchKernelGGL(wconv, dim3(O_ / 32, H_ / 64, E_), dim3(256), 0, stream, w_out, wtout, H_, O_);

    // expert MLP: 3 GEMMs
    hipLaunchKernelGGL(expert_gemm, dim3(32, H_ / 128, E_), dim3(256), 0, stream,
                       A1, wtin, b_in, h1, (float*)nullptr, offs, D_, H_, 1);
    hipLaunchKernelGGL(expert_gemm, dim3(32, H_ / 128, E_), dim3(256), 0, stream,
                       h1, wth, b_h, h2, (float*)nullptr, offs, H_, H_, 1);
    hipLaunchKernelGGL(expert_gemm, dim3(32, O_ / 128, E_), dim3(256), 0, stream,
                       h2, wtout, b_out, (u16*)nullptr, eo, offs, H_, O_, 0);

    // weighted combine -> out (fully written, no zero-init needed)
    hipLaunchKernelGGL(combine_out, dim3(B_), dim3(256), 0, stream, eo, slot, t2w, out);
}

// Round 3
// 838.073 us; speedup vs baseline: 1.6668x; 1.4562x over previous
//
#include <hip/hip_runtime.h>
#include <stdint.h>

#define E_ 8
#define D_ 1024
#define H_ 2048
#define O_ 1024
#define B_ 4096
#define GTOT (B_ * 2)        // total compact rows (every token to exactly 2 experts)
#define GPAD (GTOT + 128)    // pad: GEMM tiles may over-read up to 127 rows past count
#define MT_MAX 16            // covers cnt up to 2048 rows/expert (balanced gating: ~1024±30)

typedef __attribute__((ext_vector_type(8))) __bf16 bf16x8;
typedef __attribute__((ext_vector_type(4))) float f32x4;
typedef unsigned short u16;
typedef __attribute__((ext_vector_type(4))) u16 u16x4;
typedef __attribute__((ext_vector_type(8))) u16 u16x8;

__device__ __forceinline__ u16 f2bf(float f) {
    union { float f; uint32_t u; } v; v.f = f;
    uint32_t u = v.u;
    return (u16)((u + 0x7FFFu + ((u >> 16) & 1u)) >> 16);   // RNE
}

// async global->LDS, 16B per lane; LDS dest = base + lane*16 (wave-uniform base)
__device__ __forceinline__ void gl2lds16(const void* g, void* lds) {
    __builtin_amdgcn_global_load_lds(
        (__attribute__((address_space(1))) void*)(uintptr_t)g,
        (__attribute__((address_space(3))) void*)(uint32_t)(uintptr_t)lds,
        16, 0, 0);
}

struct XPtrs { const float* p[8]; };

// ---------------- gating: 1 wave per token, fp64 accumulation ----------------
__global__ void __launch_bounds__(256) gate_kernel(XPtrs xs, const float* __restrict__ gw,
                                                   const float* __restrict__ gb,
                                                   int* __restrict__ t2i, float* __restrict__ t2w) {
    int wave = threadIdx.x >> 6;
    int lane = threadIdx.x & 63;
    int b = blockIdx.x * 4 + wave;
    double acc[8];
#pragma unroll
    for (int e = 0; e < 8; ++e) acc[e] = 0.0;
    for (int ep = 0; ep < 8; ++ep) {
        const float* xr = xs.p[ep] + (size_t)b * D_;
        for (int t = 0; t < D_ / 64; ++t) {
            int d = t * 64 + lane;
            float v = xr[d];
            const float* g = gw + ((size_t)(ep * D_ + d)) * 8;
#pragma unroll
            for (int e = 0; e < 8; ++e) acc[e] += (double)v * (double)g[e];
        }
    }
#pragma unroll
    for (int e = 0; e < 8; ++e)
        for (int off = 32; off > 0; off >>= 1) acc[e] += __shfl_xor(acc[e], off, 64);
    if (lane == 0) {
        float lg[8];
#pragma unroll
        for (int e = 0; e < 8; ++e) lg[e] = (float)acc[e] + gb[e];
        int i0 = 0;
        for (int e = 1; e < 8; ++e) if (lg[e] > lg[i0]) i0 = e;   // strict > : lowest idx on tie
        int i1 = -1;
        for (int e = 0; e < 8; ++e) {
            if (e == i0) continue;
            if (i1 < 0 || lg[e] > lg[i1]) i1 = e;
        }
        float ex = expf(lg[i1] - lg[i0]);
        float w0 = 1.0f / (1.0f + ex);
        t2i[b * 2 + 0] = i0; t2i[b * 2 + 1] = i1;
        t2w[b * 2 + 0] = w0; t2w[b * 2 + 1] = ex * w0;
    }
}

// ---------------- routing: counts -> offsets (single block) ----------------
__global__ void __launch_bounds__(256) route_build(const int* __restrict__ t2i,
                                                   int* __restrict__ offs, int* __restrict__ cursor) {
    __shared__ int cnt[8];
    int t = threadIdx.x;
    if (t < 8) cnt[t] = 0;
    __syncthreads();
    for (int i = t; i < B_ * 2; i += 256) atomicAdd(&cnt[t2i[i]], 1);
    __syncthreads();
    if (t == 0) {
        int run = 0;
        for (int e = 0; e < 8; ++e) { offs[e] = run; cursor[e] = run; run += cnt[e]; }
        offs[8] = run;
    }
}

__global__ void __launch_bounds__(256) route_scatter(const int* __restrict__ t2i, int* __restrict__ cursor,
                                                     int* __restrict__ tok, int* __restrict__ etok,
                                                     int* __restrict__ slot) {
    int b = blockIdx.x * 256 + threadIdx.x;
#pragma unroll
    for (int j = 0; j < 2; ++j) {
        int e = t2i[b * 2 + j];
        int g = atomicAdd(&cursor[e], 1);
        tok[g] = b; etok[g] = e; slot[b * 2 + j] = g;
    }
}

// ---------------- gather tokens into compact bf16 A1 [GTOT][D] ----------------
__global__ void __launch_bounds__(256) gather_x(XPtrs xs, const int* __restrict__ tok,
                                                const int* __restrict__ etok, u16* __restrict__ A1) {
    int g = blockIdx.x;
    int t = threadIdx.x;
    const float4* s4 = (const float4*)(xs.p[etok[g]] + (size_t)tok[g] * D_);
    float4 v = s4[t];
    u16x4 o; o.x = f2bf(v.x); o.y = f2bf(v.y); o.z = f2bf(v.z); o.w = f2bf(v.w);
    ((u16x4*)(A1 + (size_t)g * D_))[t] = o;
}

// ---------------- weight transpose-convert: [E][K][N] f32 -> [E][N][K] bf16 ----------------
// tile: 64 k x 32 n; writes 16B per thread (128B contiguous per n-row)
__global__ void __launch_bounds__(256) wconv(const float* __restrict__ w, u16* __restrict__ wt,
                                             int K, int N) {
    __shared__ float tile[64][33];
    int e = blockIdx.z;
    int n0 = blockIdx.x * 32, k0 = blockIdx.y * 64;
    int tid = threadIdx.x;
    int tx = tid & 31, ty = tid >> 5;
    const float* wp = w + (size_t)e * K * N + (size_t)k0 * N + n0;
#pragma unroll
    for (int r = 0; r < 8; ++r)
        tile[ty + r * 8][tx] = wp[(size_t)(ty + r * 8) * N + tx];
    __syncthreads();
    int n = tid >> 3, kq = tid & 7;
    u16x8 o;
#pragma unroll
    for (int i = 0; i < 8; ++i) o[i] = f2bf(tile[kq * 8 + i][n]);
    u16* op = wt + (size_t)e * N * K + (size_t)(n0 + n) * K + k0 + kq * 8;
    *(u16x8*)op = o;
}

// ---------------- expert GEMM: C[cnt x N] = A[cnt x K] * Wt[e]^T (+bias, relu) ----------------
// 128x128 tile, BK=32, 4 waves; 3-stage pipeline (prefetch distance 2, vmcnt(4), one raw
// s_barrier per step). 1-D grid with XCD affinity: blockIdx & 7 = expert -> all of expert e's
// blocks land on XCD e (round-robin id%8); mt fastest within expert so the expert's A matrix
// stays hot in that XCD's 4MB L2 while B strips stream with 8 temporally-aligned sharers.
__global__ void __launch_bounds__(256) expert_gemm(const u16* __restrict__ A, const u16* __restrict__ Wt,
                                                   const float* __restrict__ bias,
                                                   u16* __restrict__ outB, float* __restrict__ outF,
                                                   const int* __restrict__ offs, int K, int N, int relu) {
    int bid = blockIdx.x;
    int e = bid & 7;
    int j = bid >> 3;
    int mt = j & (MT_MAX - 1);
    int nt = j >> 4;
    int row0 = offs[e];
    int cnt = offs[e + 1] - row0;
    if (mt * 128 >= cnt) return;

    __shared__ __align__(16) u16 sA[3][128 * 32];
    __shared__ __align__(16) u16 sB[3][128 * 32];

    int tid = threadIdx.x;
    int wave = tid >> 6, lane = tid & 63;
    int wm = wave & 1, wn = wave >> 1;
    int l15 = lane & 15, quad = lane >> 4;
    int rsub = lane >> 2;                                    // 0..15 row within 16-row chunk
    // swizzle: logical k-chunk kc of row r lives at phys chunk kc ^ g(r), g(r)=(r&3)^((r>>2)&3)
    int koff = (((lane & 3) ^ (rsub & 3) ^ ((rsub >> 2) & 3)) * 8);   // global k offset for this lane's slot
    int physOff = (quad ^ (l15 & 3) ^ ((l15 >> 2) & 3)) * 8;          // LDS chunk offset for fragment reads

    f32x4 acc[4][4];
#pragma unroll
    for (int i = 0; i < 4; ++i)
#pragma unroll
        for (int jj = 0; jj < 4; ++jj) acc[i][jj] = (f32x4){0.f, 0.f, 0.f, 0.f};

    const u16* Abase = A + (size_t)(row0 + mt * 128) * K;
    const u16* Bbase = Wt + ((size_t)e * N + (size_t)nt * 128) * K;

    int kSteps = K / 32;

    auto issue = [&](int ks, int bufIdx) {
        int k0 = ks * 32;
        u16* dA = &sA[bufIdx][0];
        u16* dB = &sB[bufIdx][0];
#pragma unroll
        for (int c = 0; c < 2; ++c) {
            int ch = wave * 2 + c;                 // 0..7, 16 rows each
            int r = ch * 16 + rsub;
            gl2lds16(Abase + (size_t)r * K + k0 + koff, dA + ch * 512);
            gl2lds16(Bbase + (size_t)r * K + k0 + koff, dB + ch * 512);
        }
    };

    issue(0, 0);
    issue(1, 1);
    int bc = 0, bi = 2;
    for (int ks = 0; ks < kSteps; ++ks) {
        // vmcnt(4): step-ks loads landed (ks+1's 4 still in flight); lgkmcnt(0): prior ds_reads done
        if (ks + 1 < kSteps) __builtin_amdgcn_s_waitcnt(0x74);
        else                 __builtin_amdgcn_s_waitcnt(0x70);
        __builtin_amdgcn_s_barrier();             // all waves' step-ks loads landed; step ks-1 reads done
        if (ks + 2 < kSteps) issue(ks + 2, bi);   // overwrites buffer last read at step ks-1 (safe)

        const u16* a_ = &sA[bc][0];
        const u16* b_ = &sB[bc][0];
        bf16x8 af[4], bfr[4];
#pragma unroll
        for (int tm = 0; tm < 4; ++tm) {
            int row = wm * 64 + tm * 16 + l15;
            af[tm] = *(const bf16x8*)(a_ + row * 32 + physOff);
        }
#pragma unroll
        for (int tn = 0; tn < 4; ++tn) {
            int row = wn * 64 + tn * 16 + l15;
            bfr[tn] = *(const bf16x8*)(b_ + row * 32 + physOff);
        }
#pragma unroll
        for (int tm = 0; tm < 4; ++tm)
#pragma unroll
            for (int tn = 0; tn < 4; ++tn)
                acc[tm][tn] = __builtin_amdgcn_mfma_f32_16x16x32_bf16(af[tm], bfr[tn], acc[tm][tn], 0, 0, 0);

        bc = (bc == 2) ? 0 : bc + 1;
        bi = (bi == 2) ? 0 : bi + 1;
    }

    // epilogue: C/D layout col=lane&15, row=quad*4+reg
    size_t gm0 = (size_t)row0 + (size_t)mt * 128 + (size_t)wm * 64;
    int lm0 = mt * 128 + wm * 64;
    int n0 = nt * 128 + wn * 64;
#pragma unroll
    for (int tn = 0; tn < 4; ++tn) {
        int col = n0 + tn * 16 + l15;
        float bv = bias[e * N + col];
#pragma unroll
        for (int tm = 0; tm < 4; ++tm) {
#pragma unroll
            for (int r = 0; r < 4; ++r) {
                int rr = tm * 16 + quad * 4 + r;
                if (lm0 + rr < cnt) {
                    float v = acc[tm][tn][r] + bv;
                    if (relu) v = fmaxf(v, 0.f);
                    if (outB) outB[(gm0 + rr) * N + col] = f2bf(v);
                    else      outF[(gm0 + rr) * N + col] = v;
                }
            }
        }
    }
}

// ---------------- combine: out[b] = w0*eo[slot0] + w1*eo[slot1] ----------------
__global__ void __launch_bounds__(256) combine_out(const float* __restrict__ eo, const int* __restrict__ slot,
                                                   const float* __restrict__ t2w, float* __restrict__ out) {
    int b = blockIdx.x, t = threadIdx.x;
    int g0 = slot[b * 2 + 0], g1 = slot[b * 2 + 1];
    float w0 = t2w[b * 2 + 0], w1 = t2w[b * 2 + 1];
    float4 va = ((const float4*)(eo + (size_t)g0 * O_))[t];
    float4 vc = ((const float4*)(eo + (size_t)g1 * O_))[t];
    float4 r;
    r.x = w0 * va.x + w1 * vc.x;
    r.y = w0 * va.y + w1 * vc.y;
    r.z = w0 * va.z + w1 * vc.z;
    r.w = w0 * va.w + w1 * vc.w;
    ((float4*)(out + (size_t)b * O_))[t] = r;
}

extern "C" void kernel_launch(void* const* d_in, const int* in_sizes, int n_in,
                              void* d_out, int out_size, void* d_ws, size_t ws_size,
                              hipStream_t stream) {
    (void)in_sizes; (void)n_in; (void)out_size; (void)ws_size;
    XPtrs xp;
    for (int i = 0; i < 8; ++i) xp.p[i] = (const float*)d_in[i];
    const float* gate_w = (const float*)d_in[8];
    const float* gate_b = (const float*)d_in[9];
    const float* w_in  = (const float*)d_in[10];
    const float* b_in  = (const float*)d_in[11];
    const float* w_h   = (const float*)d_in[12];
    const float* b_h   = (const float*)d_in[13];
    const float* w_out = (const float*)d_in[14];
    const float* b_out = (const float*)d_in[15];
    float* out = (float*)d_out;

    char* ws = (char*)d_ws;
    size_t off = 0;
    auto alloc = [&](size_t b) { size_t o = off; off += (b + 255) & ~(size_t)255; return o; };

    size_t t2i_o  = alloc((size_t)B_ * 2 * 4);
    size_t t2w_o  = alloc((size_t)B_ * 2 * 4);
    size_t slot_o = alloc((size_t)B_ * 2 * 4);
    size_t tok_o  = alloc((size_t)GTOT * 4);
    size_t etok_o = alloc((size_t)GTOT * 4);
    size_t offs_o = alloc(16 * 4);
    size_t cur_o  = alloc(8 * 4);
    size_t A1_o   = alloc((size_t)GPAD * D_ * 2);      // bf16 gathered inputs
    size_t h1_o   = alloc((size_t)GPAD * H_ * 2);      // bf16
    size_t h2_o   = alloc((size_t)GPAD * H_ * 2);      // bf16
    size_t wtin_o = alloc((size_t)E_ * H_ * D_ * 2);   // bf16 [e][n][k]
    size_t wth_o  = alloc((size_t)E_ * H_ * H_ * 2);
    size_t wtout_o= alloc((size_t)E_ * O_ * H_ * 2);
    size_t eo_o   = A1_o;   // alias: A1+h1 dead by the time layer-3 writes eo

    int*   t2i  = (int*)(ws + t2i_o);
    float* t2w  = (float*)(ws + t2w_o);
    int*   slot = (int*)(ws + slot_o);
    int*   tok  = (int*)(ws + tok_o);
    int*   etok = (int*)(ws + etok_o);
    int*   offs = (int*)(ws + offs_o);
    int*   cur  = (int*)(ws + cur_o);
    u16*   A1   = (u16*)(ws + A1_o);
    u16*   h1   = (u16*)(ws + h1_o);
    u16*   h2   = (u16*)(ws + h2_o);
    u16*   wtin = (u16*)(ws + wtin_o);
    u16*   wth  = (u16*)(ws + wth_o);
    u16*   wtout= (u16*)(ws + wtout_o);
    float* eo   = (float*)(ws + eo_o);

    // gating + routing
    hipLaunchKernelGGL(gate_kernel, dim3(B_ / 4), dim3(256), 0, stream, xp, gate_w, gate_b, t2i, t2w);
    hipLaunchKernelGGL(route_build, dim3(1), dim3(256), 0, stream, t2i, offs, cur);
    hipLaunchKernelGGL(route_scatter, dim3(B_ / 256), dim3(256), 0, stream, t2i, cur, tok, etok, slot);
    hipLaunchKernelGGL(gather_x, dim3(GTOT), dim3(256), 0, stream, xp, tok, etok, A1);

    // weight convert+transpose (fp32 [E][K][N] -> bf16 [E][N][K])
    hipLaunchKernelGGL(wconv, dim3(H_ / 32, D_ / 64, E_), dim3(256), 0, stream, w_in, wtin, D_, H_);
    hipLaunchKernelGGL(wconv, dim3(H_ / 32, H_ / 64, E_), dim3(256), 0, stream, w_h, wth, H_, H_);
    hipLaunchKernelGGL(wconv, dim3(O_ / 32, H_ / 64, E_), dim3(256), 0, stream, w_out, wtout, H_, O_);

    // expert MLP: 3 GEMMs (1-D grid, XCD-affine: id&7 = expert, mt fastest)
    hipLaunchKernelGGL(expert_gemm, dim3(E_ * MT_MAX * (H_ / 128)), dim3(256), 0, stream,
                       A1, wtin, b_in, h1, (float*)nullptr, offs, D_, H_, 1);
    hipLaunchKernelGGL(expert_gemm, dim3(E_ * MT_MAX * (H_ / 128)), dim3(256), 0, stream,
                       h1, wth, b_h, h2, (float*)nullptr, offs, H_, H_, 1);
    hipLaunchKernelGGL(expert_gemm, dim3(E_ * MT_MAX * (O_ / 128)), dim3(256), 0, stream,
                       h2, wtout, b_out, (u16*)nullptr, eo, offs, H_, O_, 0);

    // weighted combine -> out (fully written, no zero-init needed)
    hipLaunchKernelGGL(combine_out, dim3(B_), dim3(256), 0, stream, eo, slot, t2w, out);
}